// Round 1
// baseline (326.513 us; speedup 1.0000x reference)
//
#include <hip/hip_runtime.h>
#include <stdint.h>
#include <stddef.h>

// Problem constants (AttentiveTransformer: B=65536, D_IN=128, F=512, fp32)
#define NROWS 65536
#define DK 128
#define NF 512
#define BN_EPS 1e-3f

typedef __attribute__((ext_vector_type(8))) short short8;   // 8 x bf16 (4 VGPR)
typedef __attribute__((ext_vector_type(4))) float f32x4;    // MFMA accumulator

__device__ __forceinline__ unsigned short f2bf(float f) {
  unsigned int u = __builtin_bit_cast(unsigned int, f);
  u += 0x7fffu + ((u >> 16) & 1u);     // round-to-nearest-even
  return (unsigned short)(u >> 16);
}
__device__ __forceinline__ float bf2f(unsigned short h) {
  unsigned int u = ((unsigned int)h) << 16;
  return __builtin_bit_cast(float, u);
}

// ---------------------------------------------------------------------------
// Prep: blocks 0..255 transpose W [128][512] -> Wt hi/lo bf16 [512][128];
//       block 256 computes folded BN coefficients alpha/delta per column.
// ---------------------------------------------------------------------------
__global__ void prep_kernel(const float* __restrict__ W,
                            const float* __restrict__ bias,
                            const float* __restrict__ gamma,
                            const float* __restrict__ beta,
                            const float* __restrict__ mean,
                            const float* __restrict__ var,
                            unsigned short* __restrict__ wt_hi,
                            unsigned short* __restrict__ wt_lo,
                            float* __restrict__ alpha,
                            float* __restrict__ delta) {
  int bid = blockIdx.x;
  int tid = threadIdx.x;
  if (bid < 256) {
    int idx = bid * 256 + tid;        // 0..65535 over [128][512]
    int d = idx >> 9;                 // k index 0..127
    int f = idx & 511;                // col index 0..511
    float w = W[idx];
    unsigned short wh = f2bf(w);
    float rem = w - bf2f(wh);
    unsigned short wl = f2bf(rem);
    wt_hi[(size_t)f * DK + d] = wh;
    wt_lo[(size_t)f * DK + d] = wl;
  } else {
#pragma unroll
    for (int i = 0; i < 2; ++i) {
      int f = tid + i * 256;
      float a = gamma[f] * rsqrtf(var[f] + BN_EPS);
      alpha[f] = a;
      delta[f] = (bias[f] - mean[f]) * a + beta[f];
    }
  }
}

// ---------------------------------------------------------------------------
// Fused: GEMM (split-bf16 MFMA) + BN -> LDS, then per-row prior*sparsemax.
// Block = 256 threads (4 waves), 32 rows per block, all 512 cols.
//   Phase 1: wave w computes cols [128w,128w+128) for all 32 rows.
//            A frag: lane holds inputs[r0+m*16+(l&15)][kk*32+(l>>4)*8+j]
//            B frag: lane holds Wt[n][same k] (B^T layout, same as A) -
//            verified m97 gemm_bt pattern.  C/D: col=l&15, row=(l>>4)*4+reg.
//   Phase 2: quad (16 lanes) owns one full row; Michelot sparsemax with
//            4-step xor-shuffle reductions; float4 prior loads / out stores.
// ---------------------------------------------------------------------------
__global__ __launch_bounds__(256, 2) void fused_kernel(
    const float* __restrict__ inp,            // [65536][128]
    const float* __restrict__ prior,          // [65536][512]
    const unsigned short* __restrict__ wt_hi, // [512][128] bf16 hi
    const unsigned short* __restrict__ wt_lo, // [512][128] bf16 lo
    const float* __restrict__ alpha,          // [512]
    const float* __restrict__ delta,          // [512]
    float* __restrict__ out) {                // [65536][512]
  __shared__ float zsh[32][NF];               // 64 KiB, BN-ed GEMM result

  const int tid = threadIdx.x;
  const int w = tid >> 6;        // wave 0..3
  const int l = tid & 63;        // lane
  const int q = l >> 4;          // quad 0..3
  const int li = l & 15;
  const int r0 = blockIdx.x * 32;
  const int n0 = w * 128;

  // ---- Phase 1a: load + split-convert all A fragments (held in regs) ----
  short8 ah[2][4], al[2][4];
#pragma unroll
  for (int m = 0; m < 2; ++m) {
    const float* arow = inp + (size_t)(r0 + m * 16 + li) * DK + q * 8;
#pragma unroll
    for (int kk = 0; kk < 4; ++kk) {
      const float* ap = arow + kk * 32;
      float4 v0 = *(const float4*)ap;
      float4 v1 = *(const float4*)(ap + 4);
      float av[8] = {v0.x, v0.y, v0.z, v0.w, v1.x, v1.y, v1.z, v1.w};
      short8 h, lo;
#pragma unroll
      for (int j = 0; j < 8; ++j) {
        unsigned short hb = f2bf(av[j]);
        h[j] = (short)hb;
        lo[j] = (short)f2bf(av[j] - bf2f(hb));
      }
      ah[m][kk] = h;
      al[m][kk] = lo;
    }
  }

  // ---- Phase 1b: MFMA main loop, 3-product split for ~fp32 accuracy ----
  f32x4 acc[2][8];
#pragma unroll
  for (int m = 0; m < 2; ++m)
#pragma unroll
    for (int t = 0; t < 8; ++t)
      acc[m][t] = (f32x4){0.f, 0.f, 0.f, 0.f};

#pragma unroll
  for (int t = 0; t < 8; ++t) {
    const unsigned short* wbh = wt_hi + (size_t)(n0 + t * 16 + li) * DK + q * 8;
    const unsigned short* wbl = wt_lo + (size_t)(n0 + t * 16 + li) * DK + q * 8;
#pragma unroll
    for (int kk = 0; kk < 4; ++kk) {
      short8 bh = *(const short8*)(wbh + kk * 32);
      short8 bl = *(const short8*)(wbl + kk * 32);
      acc[0][t] = __builtin_amdgcn_mfma_f32_16x16x32_bf16(ah[0][kk], bh, acc[0][t], 0, 0, 0);
      acc[1][t] = __builtin_amdgcn_mfma_f32_16x16x32_bf16(ah[1][kk], bh, acc[1][t], 0, 0, 0);
      acc[0][t] = __builtin_amdgcn_mfma_f32_16x16x32_bf16(al[0][kk], bh, acc[0][t], 0, 0, 0);
      acc[1][t] = __builtin_amdgcn_mfma_f32_16x16x32_bf16(al[1][kk], bh, acc[1][t], 0, 0, 0);
      acc[0][t] = __builtin_amdgcn_mfma_f32_16x16x32_bf16(ah[0][kk], bl, acc[0][t], 0, 0, 0);
      acc[1][t] = __builtin_amdgcn_mfma_f32_16x16x32_bf16(ah[1][kk], bl, acc[1][t], 0, 0, 0);
    }
  }

  // ---- Phase 1c: BN epilogue -> LDS ----
#pragma unroll
  for (int t = 0; t < 8; ++t) {
    int col = n0 + t * 16 + li;
    float a = alpha[col];
    float dl = delta[col];
#pragma unroll
    for (int m = 0; m < 2; ++m) {
#pragma unroll
      for (int r = 0; r < 4; ++r) {
        zsh[m * 16 + q * 4 + r][col] = fmaf(acc[m][t][r], a, dl);
      }
    }
  }
  __syncthreads();

  // ---- Phase 2: per-row prior-scaled sparsemax (quad = one row) ----
#pragma unroll
  for (int sub = 0; sub < 2; ++sub) {
    int trow = w * 8 + sub * 4 + q;        // 0..31, all distinct
    size_t grow = (size_t)(r0 + trow);
    float z[32];
    const float* prow = prior + grow * NF + li * 4;
#pragma unroll
    for (int j = 0; j < 8; ++j) {
      float4 zv = *(const float4*)&zsh[trow][li * 4 + 64 * j];
      float4 pv = *(const float4*)(prow + 64 * j);
      z[4 * j + 0] = zv.x * pv.x;
      z[4 * j + 1] = zv.y * pv.y;
      z[4 * j + 2] = zv.z * pv.z;
      z[4 * j + 3] = zv.w * pv.w;
    }
    // row max (reduce over 16-lane group: xor masks 1,2,4,8)
    float mx = z[0];
#pragma unroll
    for (int j = 1; j < 32; ++j) mx = fmaxf(mx, z[j]);
#pragma unroll
    for (int off = 1; off <= 8; off <<= 1) mx = fmaxf(mx, __shfl_xor(mx, off, 64));

    // Michelot fixed-point: tau <- (sum_S - 1)/|S|, S = {z > tau}
    float tau = mx - 1.0f;
    float cprev = -1.0f;
    for (int it = 0; it < 40; ++it) {
      float s = 0.0f, c = 0.0f;
#pragma unroll
      for (int j = 0; j < 32; ++j) {
        bool in = z[j] > tau;
        s += in ? z[j] : 0.0f;
        c += in ? 1.0f : 0.0f;
      }
#pragma unroll
      for (int off = 1; off <= 8; off <<= 1) {
        s += __shfl_xor(s, off, 64);
        c += __shfl_xor(c, off, 64);
      }
      tau = (s - 1.0f) / c;
      if (__all(c == cprev)) break;   // support fixed -> converged (idempotent)
      cprev = c;
    }

    float* orow = out + grow * NF + li * 4;
#pragma unroll
    for (int j = 0; j < 8; ++j) {
      float4 ov;
      ov.x = fmaxf(z[4 * j + 0] - tau, 0.0f);
      ov.y = fmaxf(z[4 * j + 1] - tau, 0.0f);
      ov.z = fmaxf(z[4 * j + 2] - tau, 0.0f);
      ov.w = fmaxf(z[4 * j + 3] - tau, 0.0f);
      *(float4*)(orow + 64 * j) = ov;
    }
  }
}

// ---------------------------------------------------------------------------
extern "C" void kernel_launch(void* const* d_in, const int* in_sizes, int n_in,
                              void* d_out, int out_size, void* d_ws, size_t ws_size,
                              hipStream_t stream) {
  const float* inp   = (const float*)d_in[0];   // [65536][128]
  const float* prior = (const float*)d_in[1];   // [65536][512]
  const float* W     = (const float*)d_in[2];   // [128][512]
  const float* bias  = (const float*)d_in[3];   // [512]
  const float* gamma = (const float*)d_in[4];
  const float* beta  = (const float*)d_in[5];
  const float* mean  = (const float*)d_in[6];
  const float* var   = (const float*)d_in[7];
  float* out = (float*)d_out;

  // workspace carve: 131072 + 131072 + 2048 + 2048 = 266240 bytes
  unsigned short* wt_hi = (unsigned short*)d_ws;
  unsigned short* wt_lo = wt_hi + (size_t)NF * DK;
  float* alpha = (float*)(wt_lo + (size_t)NF * DK);
  float* delta = alpha + NF;

  prep_kernel<<<257, 256, 0, stream>>>(W, bias, gamma, beta, mean, var,
                                       wt_hi, wt_lo, alpha, delta);
  fused_kernel<<<NROWS / 32, 256, 0, stream>>>(inp, prior, wt_hi, wt_lo,
                                               alpha, delta, out);
}